// Round 9
// baseline (282.098 us; speedup 1.0000x reference)
//
#include <hip/hip_runtime.h>
#include <math.h>

// Non-explicit FP stays separate mul/add; explicit fma models the reference's
// contraction (XLA CPU AllowFPOpFusion::Fast). NUMERICS FROZEN SINCE R3:
// absmax 1.117587e-08. Bit-exactness notes:
//  - v_pk_{fma,add,mul,sub}_f32 round each 32-bit lane exactly like scalar.
//  - fused augmented elimination == getrf+laswp+trsm bitwise.
//  - in-place progressive swap over live Q pairs + pk trailing updates:
//    HW-validated bit-exact (R8: absmax identical, VGPR 128, dur == anchor).
//  - gram upper+x2 weighting: bitwise-symmetric gram; only final f32 sum
//    order changes — established invisible.
//  - finalize fusion (THIS ROUND): same f64 atomicAdd per block, same final
//    acc/nmat f64 divide + f32 cast, executed by the LAST block (ticket
//    atomic) instead of a second dispatch. Zero arithmetic change.
//
// SESSION LEDGER (falsified on HW — do not retry):
//  - PRE-PEAK restructures (sym A2/A4 mirrors, packed ap/a4p, folded U->P/Q):
//    bit-exact but allocator lands 132-136 VGPR -> above the 128 occupancy
//    cliff (4->3 waves/SIMD, dur x1.37). Net loss ~35us.
//  - amdgpu_waves_per_eu(5): 48 VGPR, 1.2GB spill, 541us.
//  - __launch_bounds__(256,2) cap on restructured shape: spills 84MB, 121us.
//  - POST-PEAK instruction cuts (~4%): VGPR 128, dur UNCHANGED (R8) —
//    elimination region is latency-bound, not issue-bound. Kept (free).
//  - Occupancy prize (8 waves/SIMD) needs <=64 VGPR: impossible per-thread;
//    4-lane cooperative split models ~1.8x issue inflation for 2x occupancy
//    (net ~1.1x best case) — not worth the risk.
// => Kernel interior is a measured local optimum (~88us). This round attacks
//    the ~125-130us bench-vs-kernel gap: fuse finalize, drop one dispatch.
#pragma clang fp contract(off)

typedef float f2 __attribute__((ext_vector_type(2)));

static __device__ __forceinline__ f2 sp(float x) { f2 r; r.x = x; r.y = x; return r; }
static __device__ __forceinline__ f2 sel2(bool d, f2 a, f2 b) {
  f2 r; r.x = d ? a.x : b.x; r.y = d ? a.y : b.y; return r;
}
#define FMA2(A, B, C) __builtin_elementwise_fma((A), (B), (C))

// element access into row-major f2-packed 8x8: m[i*4 + (j>>1)] lane (j&1)
#define EL(m, i, j) (m[(i)*4 + ((j) >> 1)][(j) & 1])

// Full 8x8 matmul, fmaf k-chain, f2-paired over j. Bitwise == R5's scalar mm8
// (full 8-term chains; first term is a mul). Used by the rare squaring path.
__device__ __forceinline__ void mm8p(const f2* __restrict__ A,
                                     const f2* __restrict__ B,
                                     f2* __restrict__ C) {
  #pragma unroll
  for (int i = 0; i < 8; ++i) {
    #pragma unroll
    for (int c = 0; c < 4; ++c) {
      f2 s = sp(EL(A, i, 0)) * B[0*4 + c];
      #pragma unroll
      for (int k = 1; k < 8; ++k)
        s = FMA2(sp(EL(A, i, k)), B[k*4 + c], s);
      C[i*4 + c] = s;
    }
  }
}

// One thread per 8x8 block, 256-thread workgroups, NO min-waves bound:
// (256,1) leaves the allocator free; this shape measures 128 VGPR, zero
// spill, 4 waves/SIMD (peak live = aa+W+V+P = 256 floats).
__global__ __launch_bounds__(256, 1)
void triality_kernel(const float* __restrict__ in, double* __restrict__ acc,
                     unsigned* __restrict__ ticket, float* __restrict__ out,
                     int nmat)
{
  const int t = blockIdx.x * 256 + threadIdx.x;
  const float4* src = (const float4*)(in + (size_t)t * 64);

  float p[64];
  #pragma unroll
  for (int i = 0; i < 16; ++i) {
    float4 q4 = src[i];
    p[4*i+0] = q4.x; p[4*i+1] = q4.y; p[4*i+2] = q4.z; p[4*i+3] = q4.w;
  }

  // A = 0.5*(P - P^T), all 64 entries each with its own sub+mul (R5 exact;
  // diag = +0 exactly).
  f2 aa[32];
  #pragma unroll
  for (int i = 0; i < 8; ++i)
    #pragma unroll
    for (int j = 0; j < 8; ++j)
      EL(aa, i, j) = 0.5f * (p[i*8+j] - p[j*8+i]);

  // 1-norm: per column j, cs = sum_i |a[i][j]| in ascending i (incl. diag +0),
  // then running max — identical op order to R5.
  float l1 = 0.0f;
  #pragma unroll
  for (int j = 0; j < 8; ++j) {
    float cs = 0.0f;
    #pragma unroll
    for (int i = 0; i < 8; ++i) cs = cs + fabsf(EL(aa, i, j));
    l1 = fmaxf(l1, cs);
  }

  // n_squarings = max(0, floor(log2(A_L1 / 3.925724783138660)))
  float fl = floorf(log2f(l1 / 3.925724783138660f));
  int ns = (fl > 0.0f) ? (int)fl : 0;
  if (ns > 0) {
    f2 sc = sp(exp2f((float)(-ns)));   // exact power of two
    #pragma unroll
    for (int e = 0; e < 32; ++e) aa[e] = aa[e] * sc;   // pk_mul, per-lane exact
  }

  // A2 = A*A  (full 8-term fmaf chains, j-paired)
  f2 a2[32];
  #pragma unroll
  for (int i = 0; i < 8; ++i)
    #pragma unroll
    for (int c = 0; c < 4; ++c) {
      f2 s = sp(EL(aa, i, 0)) * aa[0*4 + c];
      #pragma unroll
      for (int k = 1; k < 8; ++k)
        s = FMA2(sp(EL(aa, i, k)), aa[k*4 + c], s);
      a2[i*4 + c] = s;
    }

  // A4 = A2*A2
  f2 a4[32];
  #pragma unroll
  for (int i = 0; i < 8; ++i)
    #pragma unroll
    for (int c = 0; c < 4; ++c) {
      f2 s = sp(EL(a2, i, 0)) * a2[0*4 + c];
      #pragma unroll
      for (int k = 1; k < 8; ++k)
        s = FMA2(sp(EL(a2, i, k)), a2[k*4 + c], s);
      a4[i*4 + c] = s;
    }

  // A6 = A4*A2
  f2 w6[32];
  #pragma unroll
  for (int i = 0; i < 8; ++i)
    #pragma unroll
    for (int c = 0; c < 4; ++c) {
      f2 s = sp(EL(a4, i, 0)) * a2[0*4 + c];
      #pragma unroll
      for (int k = 1; k < 8; ++k)
        s = FMA2(sp(EL(a4, i, k)), a2[k*4 + c], s);
      w6[i*4 + c] = s;
    }

  // XLA backend-fused polynomial combine (validated R3), j-paired:
  //   W = fma(277200, A2, fma(1512, A4, A6)) + diag(8648640)   (into w6)
  //   V = fma(1995840, A2, fma(56, A6, 25200*A4)) + diag(17297280)
  f2 vv[32];
  #pragma unroll
  for (int e = 0; e < 32; ++e) {
    f2 x6 = w6[e], x4 = a4[e], x2 = a2[e];
    f2 w = FMA2(sp(1512.0f), x4, x6);
    w = FMA2(sp(277200.0f), x2, w);
    f2 v = FMA2(sp(56.0f), x6, sp(25200.0f) * x4);
    v = FMA2(sp(1995840.0f), x2, v);
    w6[e] = w; vv[e] = v;
  }
  #pragma unroll
  for (int i = 0; i < 8; ++i) {   // diagonal adds (scalar halves)
    EL(w6, i, i) = EL(w6, i, i) + 8648640.0f;
    EL(vv, i, i) = EL(vv, i, i) + 17297280.0f;
  }

  // U = A @ W  (full chains; k==i term is fmaf(+-0,y,s)==s — R5-equivalent)
  f2 uu[32];
  #pragma unroll
  for (int i = 0; i < 8; ++i)
    #pragma unroll
    for (int c = 0; c < 4; ++c) {
      f2 s = sp(EL(aa, i, 0)) * w6[0*4 + c];
      #pragma unroll
      for (int k = 1; k < 8; ++k)
        s = FMA2(sp(EL(aa, i, k)), w6[k*4 + c], s);
      uu[i*4 + c] = s;
    }

  // P = U + V (into uu), Q = V - U (into vv) — pk add/sub, per-lane exact
  #pragma unroll
  for (int e = 0; e < 32; ++e) {
    f2 U = uu[e], V = vv[e];
    uu[e] = U + V;
    vv[e] = V - U;
  }
  f2* P = uu;
  f2* Q = vv;

  // ---- fused augmented elimination on [Q|P]: getrf(Q) + laswp(P) +
  // unit-lower trsm, interleaved per step k (bit-identical — header).
  // POST-PEAK CUTS: in-place f2 swap over live Q pairs; pk Q trailing update.
  #pragma unroll
  for (int k = 0; k < 8; ++k) {
    float amax = fabsf(EL(Q, k, k)); int jp = k;
    #pragma unroll
    for (int i = k+1; i < 8; ++i) {
      float av = fabsf(EL(Q, i, k));
      if (av > amax) { amax = av; jp = i; }   // first max, like isamax
    }
    const int c0 = k >> 1;
    // swap rows k<->jp: in-place progressive (d true at most once), Q live
    // pairs only + all P pairs
    #pragma unroll
    for (int i = k+1; i < 8; ++i) {
      bool d = (jp == i);
      #pragma unroll
      for (int c = c0; c < 4; ++c) {
        f2 qk = Q[k*4 + c], qi = Q[i*4 + c];
        Q[k*4 + c] = sel2(d, qi, qk);
        Q[i*4 + c] = sel2(d, qk, qi);
      }
      #pragma unroll
      for (int c = 0; c < 4; ++c) {
        f2 pk_ = P[k*4 + c], pi = P[i*4 + c];
        P[k*4 + c] = sel2(d, pi, pk_);
        P[i*4 + c] = sel2(d, pk_, pi);
      }
    }
    // pivot-column scale: direct IEEE divide (validated R3)
    float dk = EL(Q, k, k);
    #pragma unroll
    for (int i = k+1; i < 8; ++i) EL(Q, i, k) = EL(Q, i, k) / dk;
    // trailing updates: Q pk pairs over live columns (lik read first; dead
    // lanes j<=k get unread garbage) + P row-axpy (pk, independent elems)
    #pragma unroll
    for (int i = k+1; i < 8; ++i) {
      float lik = EL(Q, i, k);
      f2 nl = sp(-lik);
      #pragma unroll
      for (int c = c0; c < 4; ++c)
        Q[i*4 + c] = FMA2(nl, Q[k*4 + c], Q[i*4 + c]);
      #pragma unroll
      for (int c = 0; c < 4; ++c)
        P[i*4 + c] = FMA2(nl, P[k*4 + c], P[i*4 + c]);
    }
  }

  // strsm: non-unit upper, k descending, IEEE f32 divide per element
  #pragma unroll
  for (int k = 7; k >= 0; --k) {
    float dk = EL(Q, k, k);
    #pragma unroll
    for (int j = 0; j < 8; ++j) EL(P, k, j) = EL(P, k, j) / dk;
    #pragma unroll
    for (int i = 0; i < k; ++i) {
      f2 nu = sp(-EL(Q, i, k));
      #pragma unroll
      for (int c = 0; c < 4; ++c)
        P[i*4 + c] = FMA2(nu, P[k*4 + c], P[i*4 + c]);
    }
  }

  // repeated squaring (ns in {0,1} statistically)
  for (int sq = 0; sq < ns; ++sq) {
    f2 t2[32];
    mm8p(P, P, t2);
    #pragma unroll
    for (int e = 0; e < 32; ++e) P[e] = t2[e];
  }

  // gram = R^T R - I: bitwise symmetric -> compute pairs with 2c+1 >= i,
  // weight off-diag x2 (exact doubling), diag x1, duplicate-lower-lane x0.
  // Per-element chains identical; only the f32 sum order differs (invisible;
  // HW-validated R8/R9/R10/R11).
  f2 s2p = sp(0.0f);
  #pragma unroll
  for (int i = 0; i < 8; ++i) {
    #pragma unroll
    for (int c = 0; c < 4; ++c) {
      if (2*c + 1 >= i) {
        f2 g = sp(EL(P, 0, i)) * P[0*4 + c];
        #pragma unroll
        for (int j = 1; j < 8; ++j)
          g = FMA2(sp(EL(P, j, i)), P[j*4 + c], g);
        f2 idv; idv.x = (2*c == i) ? 1.0f : 0.0f;
        idv.y = (2*c + 1 == i) ? 1.0f : 0.0f;
        f2 e = g - idv;
        f2 we;
        we.x = (2*c > i) ? (e.x + e.x) : ((2*c == i) ? e.x : 0.0f);
        we.y = (2*c + 1 == i) ? e.y : (e.y + e.y);
        s2p = FMA2(we, e, s2p);
      }
    }
  }
  float frob = sqrtf(s2p.x + s2p.y);

  // wave shuffle reduce (f64) -> LDS -> one atomic per 256-thread block
  double dv = (double)frob;
  #pragma unroll
  for (int off = 32; off > 0; off >>= 1)
    dv += __shfl_down(dv, off);

  __shared__ double part[4];
  const int lane = threadIdx.x & 63;
  const int wid  = threadIdx.x >> 6;
  if (lane == 0) part[wid] = dv;
  __syncthreads();
  if (threadIdx.x == 0) {
    double s = (part[0] + part[1]) + (part[2] + part[3]);
    atomicAdd(acc, s);                     // device-scope (G12)
    __threadfence();                       // order acc-add before ticket-add
    unsigned done = atomicAdd(ticket, 1u); // device-scope ticket
    if (done == gridDim.x - 1) {
      // Last block: every other block's fence ordered its acc-add before its
      // ticket-add, and we observed all ticket-adds -> all acc-adds visible.
      __threadfence();
      double total = atomicAdd(acc, 0.0);  // coherent read (x+0.0 == x here)
      out[0] = (float)(total / (double)nmat);  // identical to old finalize
    }
  }
}

extern "C" void kernel_launch(void* const* d_in, const int* in_sizes, int n_in,
                              void* d_out, int out_size, void* d_ws, size_t ws_size,
                              hipStream_t stream) {
  const float* in = (const float*)d_in[0];
  float* out = (float*)d_out;
  double* acc = (double*)d_ws;                       // ws[0..8): f64 sum
  unsigned* ticket = (unsigned*)((char*)d_ws + 8);   // ws[8..12): block ticket
  int nmat = in_sizes[0] / 64;   // 524288
  hipMemsetAsync(d_ws, 0, 16, stream);
  triality_kernel<<<nmat / 256, 256, 0, stream>>>(in, acc, ticket, out, nmat);
}

// Round 10
// 219.268 us; speedup vs baseline: 1.2865x; 1.2865x over previous
//
#include <hip/hip_runtime.h>
#include <math.h>

// Non-explicit FP stays separate mul/add; explicit fma models the reference's
// contraction (XLA CPU AllowFPOpFusion::Fast). NUMERICS FROZEN SINCE R3:
// absmax 1.117587e-08. Bit-exactness notes:
//  - v_pk_{fma,add,mul,sub}_f32 round each 32-bit lane exactly like scalar.
//  - fused augmented elimination == getrf+laswp+trsm bitwise.
//  - in-place progressive swap over live Q pairs + pk trailing updates:
//    HW-validated bit-exact (R8: absmax identical, VGPR 128, dur == anchor).
//  - gram upper+x2 weighting: bitwise-symmetric gram; only final f32 sum
//    order changes — established invisible.
//
// SESSION LEDGER (falsified on HW — do not retry):
//  - PRE-PEAK restructures (sym A2/A4 mirrors, packed ap/a4p, folded U->P/Q):
//    bit-exact but allocator lands 132-136 VGPR -> above the 128 occupancy
//    cliff (4->3 waves/SIMD, dur x1.37). Net loss ~35us.
//  - amdgpu_waves_per_eu(5): 48 VGPR, 1.2GB spill, 541us.
//  - __launch_bounds__(256,2) cap on restructured shape: spills 84MB, 121us.
//  - POST-PEAK instruction cuts (~4%): VGPR 128, dur UNCHANGED (R8) —
//    elimination region is latency-bound, not issue-bound. Kept (free).
//  - FINALIZE FUSION (R9): last-block ticket + __threadfence per block ->
//    device-scope fence lowers to L1/L2 cache maintenance (buffer_inv class);
//    2048 invalidations poison caches for in-flight waves. Kernel 88->151us
//    (VALUBusy 65->37%), bench 220->282. The ~3us second dispatch is CHEAPER.
//    Do not fuse epilogues that need device-scope fencing.
//  - Bench-vs-kernel gap (~128us) is harness/launch-side: identical across
//    88us and 151us kernels. Not addressable from kernel code.
//  - Occupancy prize (8 waves/SIMD) needs <=64 VGPR: impossible per-thread;
//    cooperative split models <=1.1x best case at high correctness risk.
//  - divide->rcp*mul: rejected — output IS the accumulated-rounding measure;
//    ~1ulp/divide perturbs per-block frob norms at output scale. Frozen.
// => This build re-banks the best measured configuration (R8 interior +
//    two-dispatch finalize). Session practical optimum ~88us kernel.
#pragma clang fp contract(off)

typedef float f2 __attribute__((ext_vector_type(2)));

static __device__ __forceinline__ f2 sp(float x) { f2 r; r.x = x; r.y = x; return r; }
static __device__ __forceinline__ f2 sel2(bool d, f2 a, f2 b) {
  f2 r; r.x = d ? a.x : b.x; r.y = d ? a.y : b.y; return r;
}
#define FMA2(A, B, C) __builtin_elementwise_fma((A), (B), (C))

// element access into row-major f2-packed 8x8: m[i*4 + (j>>1)] lane (j&1)
#define EL(m, i, j) (m[(i)*4 + ((j) >> 1)][(j) & 1])

// Full 8x8 matmul, fmaf k-chain, f2-paired over j. Bitwise == R5's scalar mm8
// (full 8-term chains; first term is a mul). Used by the rare squaring path.
__device__ __forceinline__ void mm8p(const f2* __restrict__ A,
                                     const f2* __restrict__ B,
                                     f2* __restrict__ C) {
  #pragma unroll
  for (int i = 0; i < 8; ++i) {
    #pragma unroll
    for (int c = 0; c < 4; ++c) {
      f2 s = sp(EL(A, i, 0)) * B[0*4 + c];
      #pragma unroll
      for (int k = 1; k < 8; ++k)
        s = FMA2(sp(EL(A, i, k)), B[k*4 + c], s);
      C[i*4 + c] = s;
    }
  }
}

// One thread per 8x8 block, 256-thread workgroups, NO min-waves bound:
// (256,1) leaves the allocator free; this shape measures 128 VGPR, zero
// spill, 4 waves/SIMD (peak live = aa+W+V+P = 256 floats).
__global__ __launch_bounds__(256, 1)
void triality_kernel(const float* __restrict__ in, double* __restrict__ acc)
{
  const int t = blockIdx.x * 256 + threadIdx.x;
  const float4* src = (const float4*)(in + (size_t)t * 64);

  float p[64];
  #pragma unroll
  for (int i = 0; i < 16; ++i) {
    float4 q4 = src[i];
    p[4*i+0] = q4.x; p[4*i+1] = q4.y; p[4*i+2] = q4.z; p[4*i+3] = q4.w;
  }

  // A = 0.5*(P - P^T), all 64 entries each with its own sub+mul (R5 exact;
  // diag = +0 exactly).
  f2 aa[32];
  #pragma unroll
  for (int i = 0; i < 8; ++i)
    #pragma unroll
    for (int j = 0; j < 8; ++j)
      EL(aa, i, j) = 0.5f * (p[i*8+j] - p[j*8+i]);

  // 1-norm: per column j, cs = sum_i |a[i][j]| in ascending i (incl. diag +0),
  // then running max — identical op order to R5.
  float l1 = 0.0f;
  #pragma unroll
  for (int j = 0; j < 8; ++j) {
    float cs = 0.0f;
    #pragma unroll
    for (int i = 0; i < 8; ++i) cs = cs + fabsf(EL(aa, i, j));
    l1 = fmaxf(l1, cs);
  }

  // n_squarings = max(0, floor(log2(A_L1 / 3.925724783138660)))
  float fl = floorf(log2f(l1 / 3.925724783138660f));
  int ns = (fl > 0.0f) ? (int)fl : 0;
  if (ns > 0) {
    f2 sc = sp(exp2f((float)(-ns)));   // exact power of two
    #pragma unroll
    for (int e = 0; e < 32; ++e) aa[e] = aa[e] * sc;   // pk_mul, per-lane exact
  }

  // A2 = A*A  (full 8-term fmaf chains, j-paired)
  f2 a2[32];
  #pragma unroll
  for (int i = 0; i < 8; ++i)
    #pragma unroll
    for (int c = 0; c < 4; ++c) {
      f2 s = sp(EL(aa, i, 0)) * aa[0*4 + c];
      #pragma unroll
      for (int k = 1; k < 8; ++k)
        s = FMA2(sp(EL(aa, i, k)), aa[k*4 + c], s);
      a2[i*4 + c] = s;
    }

  // A4 = A2*A2
  f2 a4[32];
  #pragma unroll
  for (int i = 0; i < 8; ++i)
    #pragma unroll
    for (int c = 0; c < 4; ++c) {
      f2 s = sp(EL(a2, i, 0)) * a2[0*4 + c];
      #pragma unroll
      for (int k = 1; k < 8; ++k)
        s = FMA2(sp(EL(a2, i, k)), a2[k*4 + c], s);
      a4[i*4 + c] = s;
    }

  // A6 = A4*A2
  f2 w6[32];
  #pragma unroll
  for (int i = 0; i < 8; ++i)
    #pragma unroll
    for (int c = 0; c < 4; ++c) {
      f2 s = sp(EL(a4, i, 0)) * a2[0*4 + c];
      #pragma unroll
      for (int k = 1; k < 8; ++k)
        s = FMA2(sp(EL(a4, i, k)), a2[k*4 + c], s);
      w6[i*4 + c] = s;
    }

  // XLA backend-fused polynomial combine (validated R3), j-paired:
  //   W = fma(277200, A2, fma(1512, A4, A6)) + diag(8648640)   (into w6)
  //   V = fma(1995840, A2, fma(56, A6, 25200*A4)) + diag(17297280)
  f2 vv[32];
  #pragma unroll
  for (int e = 0; e < 32; ++e) {
    f2 x6 = w6[e], x4 = a4[e], x2 = a2[e];
    f2 w = FMA2(sp(1512.0f), x4, x6);
    w = FMA2(sp(277200.0f), x2, w);
    f2 v = FMA2(sp(56.0f), x6, sp(25200.0f) * x4);
    v = FMA2(sp(1995840.0f), x2, v);
    w6[e] = w; vv[e] = v;
  }
  #pragma unroll
  for (int i = 0; i < 8; ++i) {   // diagonal adds (scalar halves)
    EL(w6, i, i) = EL(w6, i, i) + 8648640.0f;
    EL(vv, i, i) = EL(vv, i, i) + 17297280.0f;
  }

  // U = A @ W  (full chains; k==i term is fmaf(+-0,y,s)==s — R5-equivalent)
  f2 uu[32];
  #pragma unroll
  for (int i = 0; i < 8; ++i)
    #pragma unroll
    for (int c = 0; c < 4; ++c) {
      f2 s = sp(EL(aa, i, 0)) * w6[0*4 + c];
      #pragma unroll
      for (int k = 1; k < 8; ++k)
        s = FMA2(sp(EL(aa, i, k)), w6[k*4 + c], s);
      uu[i*4 + c] = s;
    }

  // P = U + V (into uu), Q = V - U (into vv) — pk add/sub, per-lane exact
  #pragma unroll
  for (int e = 0; e < 32; ++e) {
    f2 U = uu[e], V = vv[e];
    uu[e] = U + V;
    vv[e] = V - U;
  }
  f2* P = uu;
  f2* Q = vv;

  // ---- fused augmented elimination on [Q|P]: getrf(Q) + laswp(P) +
  // unit-lower trsm, interleaved per step k (bit-identical — header).
  // POST-PEAK CUTS: in-place f2 swap over live Q pairs; pk Q trailing update.
  #pragma unroll
  for (int k = 0; k < 8; ++k) {
    float amax = fabsf(EL(Q, k, k)); int jp = k;
    #pragma unroll
    for (int i = k+1; i < 8; ++i) {
      float av = fabsf(EL(Q, i, k));
      if (av > amax) { amax = av; jp = i; }   // first max, like isamax
    }
    const int c0 = k >> 1;
    // swap rows k<->jp: in-place progressive (d true at most once), Q live
    // pairs only + all P pairs
    #pragma unroll
    for (int i = k+1; i < 8; ++i) {
      bool d = (jp == i);
      #pragma unroll
      for (int c = c0; c < 4; ++c) {
        f2 qk = Q[k*4 + c], qi = Q[i*4 + c];
        Q[k*4 + c] = sel2(d, qi, qk);
        Q[i*4 + c] = sel2(d, qk, qi);
      }
      #pragma unroll
      for (int c = 0; c < 4; ++c) {
        f2 pk_ = P[k*4 + c], pi = P[i*4 + c];
        P[k*4 + c] = sel2(d, pi, pk_);
        P[i*4 + c] = sel2(d, pk_, pi);
      }
    }
    // pivot-column scale: direct IEEE divide (validated R3)
    float dk = EL(Q, k, k);
    #pragma unroll
    for (int i = k+1; i < 8; ++i) EL(Q, i, k) = EL(Q, i, k) / dk;
    // trailing updates: Q pk pairs over live columns (lik read first; dead
    // lanes j<=k get unread garbage) + P row-axpy (pk, independent elems)
    #pragma unroll
    for (int i = k+1; i < 8; ++i) {
      float lik = EL(Q, i, k);
      f2 nl = sp(-lik);
      #pragma unroll
      for (int c = c0; c < 4; ++c)
        Q[i*4 + c] = FMA2(nl, Q[k*4 + c], Q[i*4 + c]);
      #pragma unroll
      for (int c = 0; c < 4; ++c)
        P[i*4 + c] = FMA2(nl, P[k*4 + c], P[i*4 + c]);
    }
  }

  // strsm: non-unit upper, k descending, IEEE f32 divide per element
  #pragma unroll
  for (int k = 7; k >= 0; --k) {
    float dk = EL(Q, k, k);
    #pragma unroll
    for (int j = 0; j < 8; ++j) EL(P, k, j) = EL(P, k, j) / dk;
    #pragma unroll
    for (int i = 0; i < k; ++i) {
      f2 nu = sp(-EL(Q, i, k));
      #pragma unroll
      for (int c = 0; c < 4; ++c)
        P[i*4 + c] = FMA2(nu, P[k*4 + c], P[i*4 + c]);
    }
  }

  // repeated squaring (ns in {0,1} statistically)
  for (int sq = 0; sq < ns; ++sq) {
    f2 t2[32];
    mm8p(P, P, t2);
    #pragma unroll
    for (int e = 0; e < 32; ++e) P[e] = t2[e];
  }

  // gram = R^T R - I: bitwise symmetric -> compute pairs with 2c+1 >= i,
  // weight off-diag x2 (exact doubling), diag x1, duplicate-lower-lane x0.
  // Per-element chains identical; only the f32 sum order differs (invisible;
  // HW-validated R8/R9/R10/R11).
  f2 s2p = sp(0.0f);
  #pragma unroll
  for (int i = 0; i < 8; ++i) {
    #pragma unroll
    for (int c = 0; c < 4; ++c) {
      if (2*c + 1 >= i) {
        f2 g = sp(EL(P, 0, i)) * P[0*4 + c];
        #pragma unroll
        for (int j = 1; j < 8; ++j)
          g = FMA2(sp(EL(P, j, i)), P[j*4 + c], g);
        f2 idv; idv.x = (2*c == i) ? 1.0f : 0.0f;
        idv.y = (2*c + 1 == i) ? 1.0f : 0.0f;
        f2 e = g - idv;
        f2 we;
        we.x = (2*c > i) ? (e.x + e.x) : ((2*c == i) ? e.x : 0.0f);
        we.y = (2*c + 1 == i) ? e.y : (e.y + e.y);
        s2p = FMA2(we, e, s2p);
      }
    }
  }
  float frob = sqrtf(s2p.x + s2p.y);

  // wave shuffle reduce (f64) -> LDS -> one atomic per 256-thread block
  double dv = (double)frob;
  #pragma unroll
  for (int off = 32; off > 0; off >>= 1)
    dv += __shfl_down(dv, off);

  __shared__ double part[4];
  const int lane = threadIdx.x & 63;
  const int wid  = threadIdx.x >> 6;
  if (lane == 0) part[wid] = dv;
  __syncthreads();
  if (threadIdx.x == 0) {
    double s = (part[0] + part[1]) + (part[2] + part[3]);
    atomicAdd(acc, s);
  }
}

__global__ void finalize_kernel(const double* __restrict__ acc,
                                float* __restrict__ out, int nmat)
{
  out[0] = (float)(acc[0] / (double)nmat);
}

extern "C" void kernel_launch(void* const* d_in, const int* in_sizes, int n_in,
                              void* d_out, int out_size, void* d_ws, size_t ws_size,
                              hipStream_t stream) {
  const float* in = (const float*)d_in[0];
  float* out = (float*)d_out;
  double* acc = (double*)d_ws;
  int nmat = in_sizes[0] / 64;   // 524288
  hipMemsetAsync(d_ws, 0, sizeof(double), stream);
  triality_kernel<<<nmat / 256, 256, 0, stream>>>(in, acc);
  finalize_kernel<<<1, 1, 0, stream>>>(acc, out, nmat);
}

// Round 11
// 213.733 us; speedup vs baseline: 1.3199x; 1.0259x over previous
//
#include <hip/hip_runtime.h>
#include <math.h>

// Non-explicit FP stays separate mul/add; explicit fma models the reference's
// contraction (XLA CPU AllowFPOpFusion::Fast). NUMERICS FROZEN SINCE R3:
// absmax 1.117587e-08. Bit-exactness notes:
//  - v_pk_{fma,add,mul,sub}_f32 round each 32-bit lane exactly like scalar.
//  - fused augmented elimination == getrf+laswp+trsm bitwise.
//  - in-place progressive swap over live Q pairs + pk trailing updates:
//    HW-validated bit-exact (R8: absmax identical, VGPR 128, dur == anchor).
//  - gram upper+x2 weighting: bitwise-symmetric gram; only final f32 sum
//    order changes — established invisible.
//  - slot-store epilogue (THIS ROUND): per-block frob sums bit-identical;
//    block sums go to slots[blockIdx.x] (plain store, no init -> memset
//    dispatch REMOVED) and finalize does a deterministic f64 tree-reduce.
//    Old atomic order was already nondeterministic; fixed-order f64 reorder
//    is ~1e-16 relative — invisible at the 1e-8 absmax scale.
//
// SESSION LEDGER (falsified on HW — do not retry):
//  - PRE-PEAK restructures (sym A2/A4 mirrors, packed ap/a4p, folded U->P/Q):
//    bit-exact but allocator lands 132-136 VGPR -> above the 128 occupancy
//    cliff (4->3 waves/SIMD, dur x1.37). Net loss ~35us.
//  - amdgpu_waves_per_eu(5): 48 VGPR, 1.2GB spill, 541us.
//  - __launch_bounds__(256,2) cap on restructured shape: spills 84MB, 121us.
//  - POST-PEAK instruction cuts (~4%): VGPR 128, dur UNCHANGED (R8) —
//    elimination region is latency-bound, not issue-bound. Kept (free).
//  - FINALIZE FUSION (R9): last-block ticket + __threadfence per block ->
//    2048 device-scope fences poison L1/L2 for in-flight waves. Kernel
//    88->151us, bench 220->282. Second dispatch is CHEAPER than fencing.
//  - Bench-vs-kernel gap (~128us) is harness/launch-side (identical across
//    88 and 151us kernels). Only its dispatch COUNT is ours: this round
//    removes the memset node.
//  - R10 rocprof pass measured 143us @ 39% VALUBusy on R8-identical source
//    with identical bench total -> counter-replay clock artifact; trust the
//    graph-captured bench number, not a single rocprof pass.
//  - Occupancy prize (8 waves/SIMD) needs <=64 VGPR: impossible per-thread;
//    cooperative split models <=1.1x best case at high correctness risk.
//  - divide->rcp*mul: rejected — output IS the accumulated-rounding measure.
#pragma clang fp contract(off)

typedef float f2 __attribute__((ext_vector_type(2)));

static __device__ __forceinline__ f2 sp(float x) { f2 r; r.x = x; r.y = x; return r; }
static __device__ __forceinline__ f2 sel2(bool d, f2 a, f2 b) {
  f2 r; r.x = d ? a.x : b.x; r.y = d ? a.y : b.y; return r;
}
#define FMA2(A, B, C) __builtin_elementwise_fma((A), (B), (C))

// element access into row-major f2-packed 8x8: m[i*4 + (j>>1)] lane (j&1)
#define EL(m, i, j) (m[(i)*4 + ((j) >> 1)][(j) & 1])

// Full 8x8 matmul, fmaf k-chain, f2-paired over j. Bitwise == R5's scalar mm8
// (full 8-term chains; first term is a mul). Used by the rare squaring path.
__device__ __forceinline__ void mm8p(const f2* __restrict__ A,
                                     const f2* __restrict__ B,
                                     f2* __restrict__ C) {
  #pragma unroll
  for (int i = 0; i < 8; ++i) {
    #pragma unroll
    for (int c = 0; c < 4; ++c) {
      f2 s = sp(EL(A, i, 0)) * B[0*4 + c];
      #pragma unroll
      for (int k = 1; k < 8; ++k)
        s = FMA2(sp(EL(A, i, k)), B[k*4 + c], s);
      C[i*4 + c] = s;
    }
  }
}

// One thread per 8x8 block, 256-thread workgroups, NO min-waves bound:
// (256,1) leaves the allocator free; this shape measures 128 VGPR, zero
// spill, 4 waves/SIMD (peak live = aa+W+V+P = 256 floats).
// slot_mode: 1 -> write block sum to slots[blockIdx.x] (no init needed);
//            0 -> atomicAdd to slots[0] (fallback if workspace too small).
__global__ __launch_bounds__(256, 1)
void triality_kernel(const float* __restrict__ in, double* __restrict__ slots,
                     int slot_mode)
{
  const int t = blockIdx.x * 256 + threadIdx.x;
  const float4* src = (const float4*)(in + (size_t)t * 64);

  float p[64];
  #pragma unroll
  for (int i = 0; i < 16; ++i) {
    float4 q4 = src[i];
    p[4*i+0] = q4.x; p[4*i+1] = q4.y; p[4*i+2] = q4.z; p[4*i+3] = q4.w;
  }

  // A = 0.5*(P - P^T), all 64 entries each with its own sub+mul (R5 exact;
  // diag = +0 exactly).
  f2 aa[32];
  #pragma unroll
  for (int i = 0; i < 8; ++i)
    #pragma unroll
    for (int j = 0; j < 8; ++j)
      EL(aa, i, j) = 0.5f * (p[i*8+j] - p[j*8+i]);

  // 1-norm: per column j, cs = sum_i |a[i][j]| in ascending i (incl. diag +0),
  // then running max — identical op order to R5.
  float l1 = 0.0f;
  #pragma unroll
  for (int j = 0; j < 8; ++j) {
    float cs = 0.0f;
    #pragma unroll
    for (int i = 0; i < 8; ++i) cs = cs + fabsf(EL(aa, i, j));
    l1 = fmaxf(l1, cs);
  }

  // n_squarings = max(0, floor(log2(A_L1 / 3.925724783138660)))
  float fl = floorf(log2f(l1 / 3.925724783138660f));
  int ns = (fl > 0.0f) ? (int)fl : 0;
  if (ns > 0) {
    f2 sc = sp(exp2f((float)(-ns)));   // exact power of two
    #pragma unroll
    for (int e = 0; e < 32; ++e) aa[e] = aa[e] * sc;   // pk_mul, per-lane exact
  }

  // A2 = A*A  (full 8-term fmaf chains, j-paired)
  f2 a2[32];
  #pragma unroll
  for (int i = 0; i < 8; ++i)
    #pragma unroll
    for (int c = 0; c < 4; ++c) {
      f2 s = sp(EL(aa, i, 0)) * aa[0*4 + c];
      #pragma unroll
      for (int k = 1; k < 8; ++k)
        s = FMA2(sp(EL(aa, i, k)), aa[k*4 + c], s);
      a2[i*4 + c] = s;
    }

  // A4 = A2*A2
  f2 a4[32];
  #pragma unroll
  for (int i = 0; i < 8; ++i)
    #pragma unroll
    for (int c = 0; c < 4; ++c) {
      f2 s = sp(EL(a2, i, 0)) * a2[0*4 + c];
      #pragma unroll
      for (int k = 1; k < 8; ++k)
        s = FMA2(sp(EL(a2, i, k)), a2[k*4 + c], s);
      a4[i*4 + c] = s;
    }

  // A6 = A4*A2
  f2 w6[32];
  #pragma unroll
  for (int i = 0; i < 8; ++i)
    #pragma unroll
    for (int c = 0; c < 4; ++c) {
      f2 s = sp(EL(a4, i, 0)) * a2[0*4 + c];
      #pragma unroll
      for (int k = 1; k < 8; ++k)
        s = FMA2(sp(EL(a4, i, k)), a2[k*4 + c], s);
      w6[i*4 + c] = s;
    }

  // XLA backend-fused polynomial combine (validated R3), j-paired:
  //   W = fma(277200, A2, fma(1512, A4, A6)) + diag(8648640)   (into w6)
  //   V = fma(1995840, A2, fma(56, A6, 25200*A4)) + diag(17297280)
  f2 vv[32];
  #pragma unroll
  for (int e = 0; e < 32; ++e) {
    f2 x6 = w6[e], x4 = a4[e], x2 = a2[e];
    f2 w = FMA2(sp(1512.0f), x4, x6);
    w = FMA2(sp(277200.0f), x2, w);
    f2 v = FMA2(sp(56.0f), x6, sp(25200.0f) * x4);
    v = FMA2(sp(1995840.0f), x2, v);
    w6[e] = w; vv[e] = v;
  }
  #pragma unroll
  for (int i = 0; i < 8; ++i) {   // diagonal adds (scalar halves)
    EL(w6, i, i) = EL(w6, i, i) + 8648640.0f;
    EL(vv, i, i) = EL(vv, i, i) + 17297280.0f;
  }

  // U = A @ W  (full chains; k==i term is fmaf(+-0,y,s)==s — R5-equivalent)
  f2 uu[32];
  #pragma unroll
  for (int i = 0; i < 8; ++i)
    #pragma unroll
    for (int c = 0; c < 4; ++c) {
      f2 s = sp(EL(aa, i, 0)) * w6[0*4 + c];
      #pragma unroll
      for (int k = 1; k < 8; ++k)
        s = FMA2(sp(EL(aa, i, k)), w6[k*4 + c], s);
      uu[i*4 + c] = s;
    }

  // P = U + V (into uu), Q = V - U (into vv) — pk add/sub, per-lane exact
  #pragma unroll
  for (int e = 0; e < 32; ++e) {
    f2 U = uu[e], V = vv[e];
    uu[e] = U + V;
    vv[e] = V - U;
  }
  f2* P = uu;
  f2* Q = vv;

  // ---- fused augmented elimination on [Q|P]: getrf(Q) + laswp(P) +
  // unit-lower trsm, interleaved per step k (bit-identical — header).
  // POST-PEAK CUTS: in-place f2 swap over live Q pairs; pk Q trailing update.
  #pragma unroll
  for (int k = 0; k < 8; ++k) {
    float amax = fabsf(EL(Q, k, k)); int jp = k;
    #pragma unroll
    for (int i = k+1; i < 8; ++i) {
      float av = fabsf(EL(Q, i, k));
      if (av > amax) { amax = av; jp = i; }   // first max, like isamax
    }
    const int c0 = k >> 1;
    // swap rows k<->jp: in-place progressive (d true at most once), Q live
    // pairs only + all P pairs
    #pragma unroll
    for (int i = k+1; i < 8; ++i) {
      bool d = (jp == i);
      #pragma unroll
      for (int c = c0; c < 4; ++c) {
        f2 qk = Q[k*4 + c], qi = Q[i*4 + c];
        Q[k*4 + c] = sel2(d, qi, qk);
        Q[i*4 + c] = sel2(d, qk, qi);
      }
      #pragma unroll
      for (int c = 0; c < 4; ++c) {
        f2 pk_ = P[k*4 + c], pi = P[i*4 + c];
        P[k*4 + c] = sel2(d, pi, pk_);
        P[i*4 + c] = sel2(d, pk_, pi);
      }
    }
    // pivot-column scale: direct IEEE divide (validated R3)
    float dk = EL(Q, k, k);
    #pragma unroll
    for (int i = k+1; i < 8; ++i) EL(Q, i, k) = EL(Q, i, k) / dk;
    // trailing updates: Q pk pairs over live columns (lik read first; dead
    // lanes j<=k get unread garbage) + P row-axpy (pk, independent elems)
    #pragma unroll
    for (int i = k+1; i < 8; ++i) {
      float lik = EL(Q, i, k);
      f2 nl = sp(-lik);
      #pragma unroll
      for (int c = c0; c < 4; ++c)
        Q[i*4 + c] = FMA2(nl, Q[k*4 + c], Q[i*4 + c]);
      #pragma unroll
      for (int c = 0; c < 4; ++c)
        P[i*4 + c] = FMA2(nl, P[k*4 + c], P[i*4 + c]);
    }
  }

  // strsm: non-unit upper, k descending, IEEE f32 divide per element
  #pragma unroll
  for (int k = 7; k >= 0; --k) {
    float dk = EL(Q, k, k);
    #pragma unroll
    for (int j = 0; j < 8; ++j) EL(P, k, j) = EL(P, k, j) / dk;
    #pragma unroll
    for (int i = 0; i < k; ++i) {
      f2 nu = sp(-EL(Q, i, k));
      #pragma unroll
      for (int c = 0; c < 4; ++c)
        P[i*4 + c] = FMA2(nu, P[k*4 + c], P[i*4 + c]);
    }
  }

  // repeated squaring (ns in {0,1} statistically)
  for (int sq = 0; sq < ns; ++sq) {
    f2 t2[32];
    mm8p(P, P, t2);
    #pragma unroll
    for (int e = 0; e < 32; ++e) P[e] = t2[e];
  }

  // gram = R^T R - I: bitwise symmetric -> compute pairs with 2c+1 >= i,
  // weight off-diag x2 (exact doubling), diag x1, duplicate-lower-lane x0.
  // Per-element chains identical; only the f32 sum order differs (invisible;
  // HW-validated R8+).
  f2 s2p = sp(0.0f);
  #pragma unroll
  for (int i = 0; i < 8; ++i) {
    #pragma unroll
    for (int c = 0; c < 4; ++c) {
      if (2*c + 1 >= i) {
        f2 g = sp(EL(P, 0, i)) * P[0*4 + c];
        #pragma unroll
        for (int j = 1; j < 8; ++j)
          g = FMA2(sp(EL(P, j, i)), P[j*4 + c], g);
        f2 idv; idv.x = (2*c == i) ? 1.0f : 0.0f;
        idv.y = (2*c + 1 == i) ? 1.0f : 0.0f;
        f2 e = g - idv;
        f2 we;
        we.x = (2*c > i) ? (e.x + e.x) : ((2*c == i) ? e.x : 0.0f);
        we.y = (2*c + 1 == i) ? e.y : (e.y + e.y);
        s2p = FMA2(we, e, s2p);
      }
    }
  }
  float frob = sqrtf(s2p.x + s2p.y);

  // wave shuffle reduce (f64) -> LDS -> one slot store (or atomic fallback)
  double dv = (double)frob;
  #pragma unroll
  for (int off = 32; off > 0; off >>= 1)
    dv += __shfl_down(dv, off);

  __shared__ double part[4];
  const int lane = threadIdx.x & 63;
  const int wid  = threadIdx.x >> 6;
  if (lane == 0) part[wid] = dv;
  __syncthreads();
  if (threadIdx.x == 0) {
    double s = (part[0] + part[1]) + (part[2] + part[3]);
    if (slot_mode) slots[blockIdx.x] = s;   // plain store; no init needed
    else           atomicAdd(slots, s);     // fallback path
  }
}

// Deterministic f64 tree-reduce of nblk block sums, then mean -> f32.
// slot_mode==0 fallback: nblk==1 (just slots[0]).
__global__ void finalize_kernel(const double* __restrict__ slots,
                                float* __restrict__ out, int nmat, int nblk)
{
  double s = 0.0;
  for (int i = threadIdx.x; i < nblk; i += 256) s += slots[i];  // ascending
  #pragma unroll
  for (int off = 32; off > 0; off >>= 1)
    s += __shfl_down(s, off);
  __shared__ double part[4];
  const int lane = threadIdx.x & 63;
  const int wid  = threadIdx.x >> 6;
  if (lane == 0) part[wid] = s;
  __syncthreads();
  if (threadIdx.x == 0) {
    double total = (part[0] + part[1]) + (part[2] + part[3]);
    out[0] = (float)(total / (double)nmat);
  }
}

extern "C" void kernel_launch(void* const* d_in, const int* in_sizes, int n_in,
                              void* d_out, int out_size, void* d_ws, size_t ws_size,
                              hipStream_t stream) {
  const float* in = (const float*)d_in[0];
  float* out = (float*)d_out;
  double* slots = (double*)d_ws;
  int nmat = in_sizes[0] / 64;   // 524288
  int nblk = nmat / 256;         // 2048
  if ((size_t)nblk * sizeof(double) <= ws_size) {
    // slot mode: NO memset dispatch (slots overwritten each iteration)
    triality_kernel<<<nblk, 256, 0, stream>>>(in, slots, 1);
    finalize_kernel<<<1, 256, 0, stream>>>(slots, out, nmat, nblk);
  } else {
    // fallback: proven atomic path
    hipMemsetAsync(d_ws, 0, sizeof(double), stream);
    triality_kernel<<<nblk, 256, 0, stream>>>(in, slots, 0);
    finalize_kernel<<<1, 256, 0, stream>>>(slots, out, nmat, 1);
  }
}